// Round 7
// baseline (16.661 us; speedup 1.0000x reference)
//
#include <hip/hip_runtime.h>
#include <hip/hip_bf16.h>

// CTC batch cost, faithful port of the JAX reference (incl. the input_len = C
// source bug). B=512, T=512, C=128, L=64 -> S=129 states, TU=128 time steps.
//
// One 64-lane wave per batch element; lane i owns states 2i (blank, b0) and
// 2i+1 (label, b1); lane 63 also owns state 128 (b2). Scaled LINEAR-space
// recursion (no transcendentals, no memory ops on the serial chain):
//   nb0 = (b0 + b1p) * pb,  nb1 = (b0 + b1 + skip*b1p) * pl,
//   nb2 = (b2 + b1) * pb        (b1p = lane-1's b1, via DPP)
// ALL probabilities are register-resident before the loop starts:
//   pl[0..127]  = yp[t*C + lbl]   -- 128 VGPRs/lane, bulk-gathered up front
//   blank col   = 2 VGPRs/lane (pbr0/pbr1), broadcast per-step via
//                 v_readlane with an immediate (t is compile-time: full unroll)
// Every 8 steps: renorm by wave max (DPP butterfly) with an exact power-of-2
// scale (frexp/ldexp are native v_frexp_*/v_ldexp); exponent accumulates in
// an int. loss = -ln2 * (log2(b1+b2) + acc) at lane 63.

#define BB 512
#define TT 512
#define CC 128
#define LL 64
#define TU 128   // input_len = C (source bug, replicated)
#define EPSF 1e-7f
#define LN2F 0.69314718055994530942f

template <int CTRL>
__device__ __forceinline__ float dpp_f(float x) {
    const int xi = __float_as_int(x);
    return __int_as_float(__builtin_amdgcn_update_dpp(xi, xi, CTRL, 0xF, 0xF, false));
}

// lane-1's x; 0.0 into lane 0 (linear-space 'NEG'). DPP only, no LDS.
__device__ __forceinline__ float shift_up1z(float x, int lane) {
    const int xi = __float_as_int(x);
    const int sh = __builtin_amdgcn_update_dpp(xi, xi, 0x111, 0xF, 0xF, false); // row_shr:1
    const int bc = __builtin_amdgcn_update_dpp(xi, xi, 0x142, 0xF, 0xF, false); // row_bcast15
    float r = ((lane & 15) == 0) ? __int_as_float(bc) : __int_as_float(sh);
    return (lane == 0) ? 0.0f : r;
}

// wave-wide max via DPP butterfly; global max in lane 63, broadcast via readlane.
__device__ __forceinline__ float wave_max(float v) {
    v = fmaxf(v, dpp_f<0xB1>(v));   // quad_perm [1,0,3,2]
    v = fmaxf(v, dpp_f<0x4E>(v));   // quad_perm [2,3,0,1]
    v = fmaxf(v, dpp_f<0x141>(v));  // row_half_mirror
    v = fmaxf(v, dpp_f<0x140>(v));  // row_mirror
    v = fmaxf(v, dpp_f<0x142>(v));  // row_bcast15
    v = fmaxf(v, dpp_f<0x143>(v));  // row_bcast31
    return __int_as_float(__builtin_amdgcn_readlane(__float_as_int(v), 63));
}

__device__ __forceinline__ void renorm(float& b0, float& b1, float& b2,
                                       int& acc, int lane, int t_done) {
    float m = fmaxf(b0, b1);
    if (lane == 63) m = fmaxf(m, b2);
    m = (lane + 64 >= t_done) ? m : 0.0f;   // only tail-reachable lanes matter
    const float M = wave_max(m);
    int e = 0;
    (void)frexpf(M, &e);                    // native v_frexp_exp; frexpf(0)->e=0
    const float scale = ldexpf(1.0f, -e);   // exact power of two
    b0 *= scale; b1 *= scale; b2 *= scale;
    acc += e;
}

__global__ __launch_bounds__(64, 1) void ctc_wave(const int* __restrict__ y_true,
                                                  const float* __restrict__ y_pred,
                                                  float* __restrict__ out) {
    const int b = blockIdx.x;
    const int lane = threadIdx.x;
    const float* yp = y_pred + (size_t)b * TT * CC;

    const int lbl  = y_true[b * LL + lane];   // label for state 2*lane+1
    const int lblp = __shfl_up(lbl, 1);       // one-time, off the hot loop
    const bool skip = (lane >= 1) && (lbl != lblp);

    // Blank column, register-resident: pbr0 = pb[t=lane], pbr1 = pb[t=64+lane].
    const float pbr0 = yp[lane * CC + (CC - 1)];
    const float pbr1 = yp[(64 + lane) * CC + (CC - 1)];

    // All 128 per-lane label probs, bulk-gathered into registers.
    float pl[TU];
#pragma unroll
    for (int t = 0; t < TU; ++t) pl[t] = yp[t * CC + lbl];

    // t = 0 init (linear space): states 0,1 = p + eps; everything else 0.
    const float pb0 = __int_as_float(__builtin_amdgcn_readlane(__float_as_int(pbr0), 0));
    float b0 = (lane == 0) ? (pb0 + EPSF) : 0.0f;
    float b1 = (lane == 0) ? (pl[0] + EPSF) : 0.0f;
    float b2 = 0.0f;
    int acc = 0;

#pragma unroll
    for (int t = 1; t < TU; ++t) {
        const float pbv = __int_as_float(__builtin_amdgcn_readlane(
            __float_as_int((t < 64) ? pbr0 : pbr1), t & 63));
        const float pbe = pbv + EPSF;
        const float ple = pl[t] + EPSF;
        const float b1p = shift_up1z(b1, lane);
        const float nb0 = (b0 + b1p) * pbe;
        const float s1  = b0 + b1 + (skip ? b1p : 0.0f);
        const float nb1 = s1 * ple;
        const float nb2 = (b2 + b1) * pbe;
        b0 = nb0; b1 = nb1; b2 = nb2;
        if ((t & 7) == 0) renorm(b0, b1, b2, acc, lane, t);
    }

    if (lane == 63) {
        const float s = b1 + b2;             // states 127, 128
        out[b] = -LN2F * (__log2f(s) + (float)acc);
    }
}

extern "C" void kernel_launch(void* const* d_in, const int* in_sizes, int n_in,
                              void* d_out, int out_size, void* d_ws, size_t ws_size,
                              hipStream_t stream) {
    const int*   y_true = (const int*)d_in[0];
    const float* y_pred = (const float*)d_in[1];
    float*       out    = (float*)d_out;
    (void)in_sizes; (void)n_in; (void)out_size; (void)d_ws; (void)ws_size;

    ctc_wave<<<BB, 64, 0, stream>>>(y_true, y_pred, out);
}

// Round 8
// 12.423 us; speedup vs baseline: 1.3411x; 1.3411x over previous
//
#include <hip/hip_runtime.h>

// CTC batch cost, faithful port of the JAX reference (incl. the input_len = C
// source bug). B=512, T=512, C=128, L=64 -> S=129 states, TU=128 time steps.
//
// One 64-lane wave per batch element; lane i owns states 2i (blank, b0) and
// 2i+1 (label, b1); lane 63 also owns state 128 (b2). Scaled LINEAR-space
// recursion (no transcendentals / no cndmask on the serial chain):
//   nb0 = (b0 + b1p) * pbe          b1p = lane-1's b1 via ONE DPP wave_shr:1
//   nb1 = (b0 + fma(skipf,b1p,b1)) * ple
//   nb2 = (b2 + b1) * pbe           (state 128, lane-63 local)
// Blank probs (lane-uniform per t) live pre-eps'd in 2 VGPRs, broadcast by
// v_readlane with an immediate (full unroll -> t compile-time). Label probs
// stream through a 32-deep register ring (static indices; 32 outstanding
// loads cover ~900-cyc cold-HBM latency -- the harness' 536MB poison fill
// evicts L3 every replay, so replays run cold).
// Every 8 steps: renorm by wave max (DPP butterfly) with an exact power-of-2
// scale; exponent accumulates in an int. loss = -ln2*(log2(b1+b2)+acc).

#define BB 512
#define TT 512
#define CC 128
#define LL 64
#define TU 128   // input_len = C (source bug, replicated)
#define EPSF 1e-7f
#define PD 32    // prefetch ring depth (power of two)
#define LN2F 0.69314718055994530942f

template <int CTRL>
__device__ __forceinline__ float dpp_f(float x) {
    const int xi = __float_as_int(x);
    return __int_as_float(__builtin_amdgcn_update_dpp(xi, xi, CTRL, 0xF, 0xF, false));
}

// whole-wave shift-up-by-1 with zero fill into lane 0: one v_mov_dpp.
__device__ __forceinline__ float shift_up1z(float x) {
    const int xi = __float_as_int(x);
    return __int_as_float(__builtin_amdgcn_update_dpp(xi, xi, 0x138 /*wave_shr:1*/,
                                                      0xF, 0xF, true));
}

// wave-wide max via DPP butterfly; global max in lane 63, broadcast via readlane.
__device__ __forceinline__ float wave_max(float v) {
    v = fmaxf(v, dpp_f<0xB1>(v));   // quad_perm [1,0,3,2]
    v = fmaxf(v, dpp_f<0x4E>(v));   // quad_perm [2,3,0,1]
    v = fmaxf(v, dpp_f<0x141>(v));  // row_half_mirror
    v = fmaxf(v, dpp_f<0x140>(v));  // row_mirror
    v = fmaxf(v, dpp_f<0x142>(v));  // row_bcast15
    v = fmaxf(v, dpp_f<0x143>(v));  // row_bcast31
    return __int_as_float(__builtin_amdgcn_readlane(__float_as_int(v), 63));
}

__device__ __forceinline__ void renorm(float& b0, float& b1, float& b2,
                                       int& acc, int lane, int t_done) {
    float m = fmaxf(b0, b1);
    if (lane == 63) m = fmaxf(m, b2);
    m = (lane + 64 >= t_done) ? m : 0.0f;   // only tail-reachable lanes matter
    const float M = wave_max(m);
    int e = 0;
    (void)frexpf(M, &e);                    // native v_frexp_exp; frexpf(0)->e=0
    const float scale = ldexpf(1.0f, -e);   // exact power of two
    b0 *= scale; b1 *= scale; b2 *= scale;
    acc += e;
}

__global__ __launch_bounds__(64) void ctc_wave(const int* __restrict__ y_true,
                                               const float* __restrict__ y_pred,
                                               float* __restrict__ out) {
    const int b = blockIdx.x;
    const int lane = threadIdx.x;
    const float* yp = y_pred + (size_t)b * TT * CC;

    const int lbl  = y_true[b * LL + lane];   // label for state 2*lane+1
    const int lblp = __shfl_up(lbl, 1);       // one-time, off the hot loop
    const float skipf = (lane >= 1 && lbl != lblp) ? 1.0f : 0.0f;

    // Blank column (lane-uniform per t), pre-eps'd, register-resident:
    // pbr0e holds t=lane, pbr1e holds t=64+lane.
    const float pbr0e = yp[lane * CC + (CC - 1)] + EPSF;
    const float pbr1e = yp[(64 + lane) * CC + (CC - 1)] + EPSF;

    // Label-prob prefetch ring for t = 1..PD (rows <= 159 < 512: in-bounds).
    float plr[PD];
#pragma unroll
    for (int j = 0; j < PD; ++j) plr[j] = yp[(1 + j) * CC + lbl];

    // t = 0 init (linear space): states 0,1 = p + eps; everything else 0.
    const float pl0 = yp[lbl] + EPSF;
    const float pb0 = __int_as_float(__builtin_amdgcn_readlane(__float_as_int(pbr0e), 0));
    float b0 = (lane == 0) ? pb0 : 0.0f;
    float b1 = (lane == 0) ? pl0 : 0.0f;
    float b2 = 0.0f;
    int acc = 0;

#pragma unroll
    for (int t = 1; t < TU; ++t) {
        const int slot = (t - 1) & (PD - 1);      // compile-time under unroll
        const float plv = plr[slot];
        plr[slot] = yp[(t + PD) * CC + lbl];      // refill for step t+PD
        const float ple = plv + EPSF;
        const float pbe = __int_as_float(__builtin_amdgcn_readlane(
            __float_as_int((t < 64) ? pbr0e : pbr1e), t & 63));
        const float b1p = shift_up1z(b1);
        const float nb0 = (b0 + b1p) * pbe;
        const float h   = __builtin_fmaf(skipf, b1p, b1);
        const float nb1 = (b0 + h) * ple;
        const float nb2 = (b2 + b1) * pbe;
        b0 = nb0; b1 = nb1; b2 = nb2;
        if ((t & 7) == 0) renorm(b0, b1, b2, acc, lane, t);
    }

    if (lane == 63) {
        const float s = b1 + b2;                  // states 127, 128
        out[b] = -LN2F * (__log2f(s) + (float)acc);
    }
}

extern "C" void kernel_launch(void* const* d_in, const int* in_sizes, int n_in,
                              void* d_out, int out_size, void* d_ws, size_t ws_size,
                              hipStream_t stream) {
    const int*   y_true = (const int*)d_in[0];
    const float* y_pred = (const float*)d_in[1];
    float*       out    = (float*)d_out;
    (void)in_sizes; (void)n_in; (void)out_size; (void)d_ws; (void)ws_size;

    ctc_wave<<<BB, 64, 0, stream>>>(y_true, y_pred, out);
}